// Round 1
// baseline (93.734 us; speedup 1.0000x reference)
//
#include <hip/hip_runtime.h>
#include <hip/hip_bf16.h>
#include <math.h>

// M=100000 nodes, D=64, G=1024 graphs. batch sorted -> contiguous segments.
// out[g] = triu( sum_{m in seg g} a_m * x_m x_m^T ),  a = segment-softmax(x.w+b)
// Fully fused SINGLE launch:
//  - per-block wave-cooperative 64-ary lower_bound on sorted batch (no bounds
//    kernel, no workspace use at all)
//  - TKB=128 node block-tile: for n<=128 (~99% of segments) the whole segment
//    is staged once -> ONE __syncthreads in the main path (vs 4 barrier-coupled
//    tiles before). K-loop = 4 in-register k-chunks of 32 over the LDS tile.
//  - shift-free softmax (|imp| small), denom applied at epilogue.

#define DDIM 64
#define NTRI 2080          // 64*65/2
#define TKB  128           // nodes per block tile

typedef __bf16 bf16x8 __attribute__((ext_vector_type(8)));
typedef float  f32x4  __attribute__((ext_vector_type(4)));

__device__ __forceinline__ unsigned pack_bf16(float a, float b) {
    __hip_bfloat162 h2 = __float22bfloat162_rn(make_float2(a, b)); // a -> low ushort
    return *reinterpret_cast<unsigned*>(&h2);
}

__global__ void __launch_bounds__(256)
sop_kernel(const float* __restrict__ x,
           const float* __restrict__ att_w,
           const float* __restrict__ att_b,
           const int*   __restrict__ batch,
           float*       __restrict__ out,
           int M)
{
    // Transposed [feat][node] bf16 tiles; 16 pair-groups (8 nodes) per row,
    // group slot swizzled: slot = g ^ ((row>>2)&15).  A = e-scaled, B = raw.
    __shared__ unsigned short sA[DDIM * TKB];   // 16 KiB
    __shared__ unsigned short sB[DDIM * TKB];   // 16 KiB
    __shared__ float sRed[8];
    __shared__ int   sBnd[2];

    const int g    = blockIdx.x;
    const int tid  = threadIdx.x;
    const int wid  = tid >> 6;
    const int lane = tid & 63;
    const int c    = lane & 15;      // feature chunk (float4), == MFMA row il
    const int q    = lane >> 4;      // 0..3, k-subgroup

    // ---- segment bounds: wave 0 -> lower_bound(g), wave 1 -> lower_bound(g+1)
    if (wid < 2) {
        const int v = g + wid;
        int lo = 0, hi = M;
        while (hi - lo > 64) {
            const int step = (hi - lo + 63) >> 6;
            const int idx  = lo + lane * step;
            const int bv   = (idx < hi) ? batch[idx] : 0x7fffffff;
            const unsigned long long lt = __ballot(bv < v);
            const int cnt = __popcll(lt);
            if (cnt == 0) {
                hi = lo;
            } else {
                const int nhi = (cnt < 64) ? (lo + cnt * step) : hi;
                lo = lo + (cnt - 1) * step + 1;
                hi = (nhi < hi) ? nhi : hi;
            }
        }
        const int idx = lo + lane;
        const int bv  = (idx < hi) ? batch[idx] : 0x7fffffff;
        const int cnt = __popcll(__ballot(bv < v));
        if (lane == 0) sBnd[wid] = lo + cnt;
    }
    __syncthreads();

    const int s = sBnd[0];
    const int n = sBnd[1] - s;
    float* og = out + (size_t)g * NTRI;

    if (n == 0) {                                // out poisoned -> write zeros
        const f32x4 z4 = {0.f, 0.f, 0.f, 0.f};
        for (int i = tid; i < NTRI / 4; i += 256) ((f32x4*)og)[i] = z4;
        return;
    }

    const float4* x4 = (const float4*)x;
    const float4  wv = ((const float4*)att_w)[c];
    const float   bb = att_b[0];

    f32x4 acc[4];
#pragma unroll
    for (int jt = 0; jt < 4; ++jt) acc[jt] = (f32x4){0.f, 0.f, 0.f, 0.f};

    unsigned* A32 = (unsigned*)sA;
    unsigned* B32 = (unsigned*)sB;

    const int T = (n + TKB - 1) / TKB;           // == 1 for ~99% of segments
    float lsum = 0.f;                            // 16x-redundant running sum of e_m

    for (int t = 0; t < T; ++t) {
        if (t) __syncthreads();                  // protect staging (rare path)

        // this thread's 8 nodes: pair = 4*(4*jj+wid)+q  ->  node m0, m0+1
        const int mbase = t * TKB + 8 * wid + 2 * q;
        float4 p0[4], p1[4];
        float  d0[4], d1[4];
        const float4 z = {0.f, 0.f, 0.f, 0.f};
#pragma unroll
        for (int jj = 0; jj < 4; ++jj) {
            const int m0 = mbase + 32 * jj;
            p0[jj] = (m0     < n) ? x4[(size_t)(s + m0) * 16 + c]     : z;
            p1[jj] = (m0 + 1 < n) ? x4[(size_t)(s + m0 + 1) * 16 + c] : z;
        }
#pragma unroll
        for (int jj = 0; jj < 4; ++jj) {
            d0[jj] = fmaf(p0[jj].x, wv.x, fmaf(p0[jj].y, wv.y, fmaf(p0[jj].z, wv.z, p0[jj].w * wv.w)));
            d1[jj] = fmaf(p1[jj].x, wv.x, fmaf(p1[jj].y, wv.y, fmaf(p1[jj].z, wv.z, p1[jj].w * wv.w)));
        }
#pragma unroll
        for (int mk = 1; mk < 16; mk <<= 1) {    // width-16 dot reduce, 8 indep chains
#pragma unroll
            for (int jj = 0; jj < 4; ++jj) {
                d0[jj] += __shfl_xor(d0[jj], mk, 16);
                d1[jj] += __shfl_xor(d1[jj], mk, 16);
            }
        }
#pragma unroll
        for (int jj = 0; jj < 4; ++jj) {
            const int m0 = mbase + 32 * jj;
            float e0 = 0.f, e1 = 0.f;
            if (m0     < n) e0 = __expf(d0[jj] + bb);
            if (m0 + 1 < n) e1 = __expf(d1[jj] + bb);
            lsum += e0 + e1;
            const int gg = 4 * jj + wid;         // pair-group 0..15
            const float* f0 = (const float*)&p0[jj];
            const float* f1 = (const float*)&p1[jj];
#pragma unroll
            for (int jf = 0; jf < 4; ++jf) {
                // row = 4c+jf; slot = gg ^ ((row>>2)&15) = gg ^ c
                const int ui = (4 * c + jf) * 64 + (((gg ^ c) & 15) << 2) + q;
                A32[ui] = pack_bf16(e0 * f0[jf], e1 * f1[jf]);
                B32[ui] = pack_bf16(f0[jf], f1[jf]);
            }
        }
        __syncthreads();                         // the single main-path barrier

        // MFMA: 4 k-chunks of 32 nodes, acc stays in registers
        const int sAx = 4 * wid + (c >> 2);      // (row>>2)&15 for row=16*wid+c
#pragma unroll
        for (int kc = 0; kc < 4; ++kc) {
            const bf16x8 av = *(const bf16x8*)(sA + (16 * wid + c) * TKB
                                                  + ((((4 * kc + q) ^ sAx) & 15) << 3));
#pragma unroll
            for (int jt = 0; jt < 4; ++jt) {
                const int sBx = 4 * jt + (c >> 2);
                const bf16x8 bv = *(const bf16x8*)(sB + (16 * jt + c) * TKB
                                                      + ((((4 * kc + q) ^ sBx) & 15) << 3));
                acc[jt] = __builtin_amdgcn_mfma_f32_16x16x32_bf16(av, bv, acc[jt], 0, 0, 0);
            }
        }
    }

    // --- denom: wave reduce (16x overcount, exact /16) + cross-wave combine ---
#pragma unroll
    for (int off = 32; off > 0; off >>= 1) lsum += __shfl_down(lsum, off, 64);
    if (lane == 0) sRed[wid] = lsum;
    __syncthreads();
    if (tid == 0) sRed[4] = 16.0f / (sRed[0] + sRed[1] + sRed[2] + sRed[3]);
    __syncthreads();
    const float invd = sRed[4];

    // --- epilogue: C/D layout col=lane&15, row=q*4+reg -> triu scatter ---
    const int rbase = 16 * wid + q * 4;
#pragma unroll
    for (int jt = 0; jt < 4; ++jt) {
        const int j = 16 * jt + c;
#pragma unroll
        for (int r = 0; r < 4; ++r) {
            const int i = rbase + r;
            if (j >= i) og[i * DDIM - (i * (i - 1)) / 2 + (j - i)] = acc[jt][r] * invd;
        }
    }
}

extern "C" void kernel_launch(void* const* d_in, const int* in_sizes, int n_in,
                              void* d_out, int out_size, void* d_ws, size_t ws_size,
                              hipStream_t stream) {
    const float* x     = (const float*)d_in[0];
    const float* att_w = (const float*)d_in[1];
    const float* att_b = (const float*)d_in[2];
    const int*   batch = (const int*)d_in[3];
    // d_in[4] = edge: dead code in reference
    float* out = (float*)d_out;

    const int M = in_sizes[0] / DDIM;
    const int G = out_size / NTRI;

    // single fused launch; d_ws intentionally unused
    sop_kernel<<<G, 256, 0, stream>>>(x, att_w, att_b, batch, out, M);
}